// Round 1
// baseline (756.580 us; speedup 1.0000x reference)
//
#include <hip/hip_runtime.h>

// SingleGcnLayer: y = relu( ((targets ⊕ Σ_k neighbors) @ kernel) / guard(Σ a) )
// targets[32,1024,256] f32, neighbors[32,1024,16,256] f32, a[32,1024,17] f32,
// kernel[256,256] f32 -> out[32,1024,256] f32.
// Round 2: s stays in registers (no LDS round-trip); broadcast s[r][d] via
// v_readlane -> SGPR -> v_fmac. LDS holds only double-buffered 16KB kernel
// tiles. One barrier/pass. 16 waves/CU.
// Round 3 (this): drop nontemporal hint on the targets/neighbors read stream.
// The kernel is HBM-BW-bound (~604 MB/iter irreducible); the nt flag was
// forbidding Infinity-Cache retention of the 512 MB neighbor stream across
// back-to-back graph replays. Store stays nt (write-once, never read back).

typedef float v4f __attribute__((ext_vector_type(4)));

#define BB 32
#define NN 1024
#define KK 16
#define DD 256
#define LL 256
#define ROWS 32      // rows (b,n) per block; 8 per wave
#define DTILE 16     // kernel d-rows per pass
#define NPASS (DD / DTILE)
#define NTHREADS 256

__device__ __forceinline__ float bcast_lane(float x, int lane) {
    return __int_as_float(__builtin_amdgcn_readlane(__float_as_int(x), lane));
}

__global__ __launch_bounds__(NTHREADS, 4)
void gcn_fused(const float* __restrict__ targets,
               const float* __restrict__ neighbors,
               const float* __restrict__ a,
               const float* __restrict__ kern,
               float* __restrict__ out) {
    __shared__ float kt[2][DTILE * LL];   // 2 x 16 KB kernel tiles
    __shared__ float invf[ROWS];

    const int t        = threadIdx.x;
    const int w        = t >> 6;          // wave 0..3
    const int lane     = t & 63;
    const int row_base = blockIdx.x * ROWS;

    const v4f* k4 = (const v4f*)kern;

    // ---- issue tile-0 kernel stage loads first (L2-resident after block 0) ----
    v4f stage[4];
    #pragma unroll
    for (int i = 0; i < 4; ++i) stage[i] = k4[i * NTHREADS + t];

    // ---- degree factor (tiny) ----
    if (t < ROWS) {
        const float* ap = a + (size_t)(row_base + t) * (KK + 1);
        float f = 0.0f;
        #pragma unroll
        for (int j = 0; j < KK + 1; ++j) f += ap[j];
        invf[t] = (f > 0.5f) ? (1.0f / f) : 1.0f;
    }

    // ---- phase 1: sreg[r] = targets[row] + sum_k neighbors[row][k], in regs ----
    // wave w owns rows w*8..w*8+7; lane holds d = 4*lane..4*lane+3.
    const v4f* t4 = (const v4f*)targets;
    const v4f* n4 = (const v4f*)neighbors;
    v4f sreg[8];
    #pragma unroll
    for (int r = 0; r < 8; ++r) {
        const int grow = row_base + w * 8 + r;
        v4f accum = t4[(size_t)grow * (DD / 4) + lane];
        #pragma unroll 4
        for (int k = 0; k < KK; ++k) {
            accum += n4[((size_t)grow * KK + k) * (DD / 4) + lane];
        }
        sreg[r] = accum;
    }

    // ---- write tile 0, converge ----
    #pragma unroll
    for (int i = 0; i < 4; ++i)
        *(v4f*)&kt[0][(i * NTHREADS + t) * 4] = stage[i];
    __syncthreads();

    v4f acc[8];
    #pragma unroll
    for (int r = 0; r < 8; ++r) acc[r] = v4f{0.0f, 0.0f, 0.0f, 0.0f};

    // ---- phase 2: acc[r][cols 4*lane..+3] += s[r][d] * K[d][cols] ----
    for (int dt = 0; dt < NPASS; ++dt) {
        const int cur = dt & 1;
        if (dt < NPASS - 1) {   // prefetch next tile (consumed ~1 pass later)
            #pragma unroll
            for (int i = 0; i < 4; ++i)
                stage[i] = k4[(dt + 1) * (DTILE * LL / 4) + i * NTHREADS + t];
        }
        #pragma unroll
        for (int dd = 0; dd < DTILE; ++dd) {
            // K row d, this lane's 4 columns: lane-contiguous b128, conflict-free
            v4f kv = *(const v4f*)&kt[cur][dd * LL + 4 * lane];
            const int chunk = dt * (DTILE / 4) + (dd >> 2);  // wave-uniform lane idx
            #pragma unroll
            for (int r = 0; r < 8; ++r) {
                const float sv = bcast_lane(sreg[r][dd & 3], chunk); // s[r][d] -> SGPR
                acc[r] += sv * kv;   // v_fmac_f32 with SGPR operand
            }
        }
        if (dt < NPASS - 1) {
            *(v4f*)&kt[cur ^ 1][(0 * NTHREADS + t) * 4] = stage[0];
            *(v4f*)&kt[cur ^ 1][(1 * NTHREADS + t) * 4] = stage[1];
            *(v4f*)&kt[cur ^ 1][(2 * NTHREADS + t) * 4] = stage[2];
            *(v4f*)&kt[cur ^ 1][(3 * NTHREADS + t) * 4] = stage[3];
            __syncthreads();   // one barrier per pass
        }
    }

    // ---- epilogue: normalize, relu, coalesced nontemporal store ----
    #pragma unroll
    for (int r = 0; r < 8; ++r) {
        const int rl    = w * 8 + r;
        const float inv = invf[rl];
        v4f v = acc[r] * inv;
        v.x = fmaxf(v.x, 0.0f);
        v.y = fmaxf(v.y, 0.0f);
        v.z = fmaxf(v.z, 0.0f);
        v.w = fmaxf(v.w, 0.0f);
        __builtin_nontemporal_store(v, (v4f*)&out[(size_t)(row_base + rl) * LL + 4 * lane]);
    }
}

extern "C" void kernel_launch(void* const* d_in, const int* in_sizes, int n_in,
                              void* d_out, int out_size, void* d_ws, size_t ws_size,
                              hipStream_t stream) {
    const float* targets   = (const float*)d_in[0];
    const float* neighbors = (const float*)d_in[1];
    const float* a         = (const float*)d_in[2];
    const float* kern      = (const float*)d_in[3];
    float* out = (float*)d_out;
    const int blocks = (BB * NN) / ROWS;   // 1024
    gcn_fused<<<dim3(blocks), dim3(NTHREADS), 0, stream>>>(targets, neighbors, a, kern, out);
}

// Round 2
// 720.865 us; speedup vs baseline: 1.0495x; 1.0495x over previous
//
#include <hip/hip_runtime.h>

// SingleGcnLayer: y = relu( ((targets ⊕ Σ_k neighbors) @ kernel) / guard(Σ a) )
// targets[32,1024,256] f32, neighbors[32,1024,16,256] f32, a[32,1024,17] f32,
// kernel[256,256] f32 -> out[32,1024,256] f32.
// Round 4: row-group software pipeline. Grid is exactly one resident
// generation (4 blk/CU), so the old load-all-then-GEMM structure phase-locks
// the whole GPU: HBM saturated ~90us, then VALU-only GEMM ~39us with the
// memory pipe idle. Split each wave's 8 rows into 4 groups of 2; sweep the
// 16 K-tiles once per group, interleaving the NEXT group's 32 neighbor
// loads 2-per-pass (pend regs, one pass of latency slack). Exposed tail
// shrinks from ~39us to ~1 group (~10us). nt loads restored (round-1: L3
// does not retain the stream; nt was +4%).

typedef float v4f __attribute__((ext_vector_type(4)));

#define BB 32
#define NN 1024
#define KK 16
#define DD 256
#define LL 256
#define ROWS 32      // rows (b,n) per block; 8 per wave
#define DTILE 16     // kernel d-rows per pass
#define NTILES (DD / DTILE)   // 16
#define NTHREADS 256
#define NG 4         // row-groups per wave (2 rows each)

__device__ __forceinline__ float bcast_lane(float x, int lane) {
    return __int_as_float(__builtin_amdgcn_readlane(__float_as_int(x), lane));
}

__global__ __launch_bounds__(NTHREADS, 4)
void gcn_fused(const float* __restrict__ targets,
               const float* __restrict__ neighbors,
               const float* __restrict__ a,
               const float* __restrict__ kern,
               float* __restrict__ out) {
    __shared__ float kt[2][DTILE * LL];   // 2 x 16 KB kernel tiles
    __shared__ float invf[ROWS];

    const int t        = threadIdx.x;
    const int w        = t >> 6;          // wave 0..3
    const int lane     = t & 63;
    const int row_base = blockIdx.x * ROWS;
    const int wrow     = row_base + w * 8;

    const v4f* k4 = (const v4f*)kern;
    const v4f* t4 = (const v4f*)targets;
    const v4f* n4 = (const v4f*)neighbors;

    // ---- issue tile-0 kernel stage loads first (L2-resident after block 0) ----
    v4f stage[4];
    #pragma unroll
    for (int i = 0; i < 4; ++i) stage[i] = k4[i * NTHREADS + t];

    // ---- degree factor (tiny) ----
    if (t < ROWS) {
        const float* ap = a + (size_t)(row_base + t) * (KK + 1);
        float f = 0.0f;
        #pragma unroll
        for (int j = 0; j < KK + 1; ++j) f += ap[j];
        invf[t] = (f > 0.5f) ? (1.0f / f) : 1.0f;
    }

    // ---- prologue: s for group 0 (wave rows 0,1), both rows interleaved ----
    v4f sA0, sA1;
    {
        const size_t g0 = (size_t)wrow;
        const size_t g1 = (size_t)wrow + 1;
        v4f a0 = __builtin_nontemporal_load(&t4[g0 * (DD / 4) + lane]);
        v4f a1 = __builtin_nontemporal_load(&t4[g1 * (DD / 4) + lane]);
        #pragma unroll 4
        for (int k = 0; k < KK; ++k) {
            a0 += __builtin_nontemporal_load(&n4[(g0 * KK + k) * (DD / 4) + lane]);
            a1 += __builtin_nontemporal_load(&n4[(g1 * KK + k) * (DD / 4) + lane]);
        }
        sA0 = a0;
        sA1 = a1;
    }

    // ---- write tile 0, converge ----
    #pragma unroll
    for (int i = 0; i < 4; ++i)
        *(v4f*)&kt[0][(i * NTHREADS + t) * 4] = stage[i];
    __syncthreads();

    v4f acc[8];
    #pragma unroll
    for (int r = 0; r < 8; ++r) acc[r] = v4f{0.0f, 0.0f, 0.0f, 0.0f};

    v4f sB0, sB1, p0, p1;   // next group's s under construction + pend loads

    #pragma unroll
    for (int g = 0; g < NG; ++g) {          // g compile-time (unrolled): acc[] static
        for (int dt = 0; dt < NTILES; ++dt) {
            const int  cur       = dt & 1;
            const bool last_pass = (g == NG - 1) && (dt == NTILES - 1);

            // K-tile prefetch for next pass (L2-hot, consumed ~1 pass later)
            if (!last_pass) {
                const int nxt = (dt + 1) & (NTILES - 1);
                #pragma unroll
                for (int i = 0; i < 4; ++i)
                    stage[i] = k4[nxt * (DTILE * LL / 4) + i * NTHREADS + t];
            }

            if (g < NG - 1) {
                // retire last pass's pend loads into sB (order: target, k=0..15)
                if (dt == 0) {
                    const size_t nrow = (size_t)wrow + 2 * g + 2;
                    sB0 = __builtin_nontemporal_load(&t4[nrow * (DD / 4) + lane]);
                    sB1 = __builtin_nontemporal_load(&t4[(nrow + 1) * (DD / 4) + lane]);
                } else if (dt <= 8) {       // j = 2dt-2, 2dt-1 in 0..15 -> row 0
                    sB0 += p0; sB0 += p1;
                } else {                    // j = 16..29 -> row 1
                    sB1 += p0; sB1 += p1;
                }
                // issue this pass's 2 neighbor loads: j = 2dt, 2dt+1
                const size_t nrow = (size_t)wrow + 2 * g + 2 + (dt >= 8 ? 1 : 0);
                const int    k0   = (2 * dt) & 15;
                p0 = __builtin_nontemporal_load(&n4[(nrow * KK + k0) * (DD / 4) + lane]);
                p1 = __builtin_nontemporal_load(&n4[(nrow * KK + k0 + 1) * (DD / 4) + lane]);
            }

            // ---- GEMM: this group's 2 rows over K-rows d = dt*16 .. dt*16+15 ----
            #pragma unroll
            for (int dd = 0; dd < DTILE; ++dd) {
                v4f kv = *(const v4f*)&kt[cur][dd * LL + 4 * lane];
                const int chunk = dt * (DTILE / 4) + (dd >> 2);   // wave-uniform
                const float sv0 = bcast_lane(sA0[dd & 3], chunk);
                const float sv1 = bcast_lane(sA1[dd & 3], chunk);
                acc[2 * g]     += sv0 * kv;
                acc[2 * g + 1] += sv1 * kv;
            }

            if (!last_pass) {
                *(v4f*)&kt[cur ^ 1][(0 * NTHREADS + t) * 4] = stage[0];
                *(v4f*)&kt[cur ^ 1][(1 * NTHREADS + t) * 4] = stage[1];
                *(v4f*)&kt[cur ^ 1][(2 * NTHREADS + t) * 4] = stage[2];
                *(v4f*)&kt[cur ^ 1][(3 * NTHREADS + t) * 4] = stage[3];
                __syncthreads();   // one barrier per pass
            }
        }
        if (g < NG - 1) {
            sB1 += p0; sB1 += p1;   // retire j = 30,31
            sA0 = sB0;
            sA1 = sB1;
        }
    }

    // ---- epilogue: normalize, relu, coalesced nontemporal store ----
    #pragma unroll
    for (int r = 0; r < 8; ++r) {
        const int rl    = w * 8 + r;
        const float inv = invf[rl];
        v4f v = acc[r] * inv;
        v.x = fmaxf(v.x, 0.0f);
        v.y = fmaxf(v.y, 0.0f);
        v.z = fmaxf(v.z, 0.0f);
        v.w = fmaxf(v.w, 0.0f);
        __builtin_nontemporal_store(v, (v4f*)&out[(size_t)(row_base + rl) * LL + 4 * lane]);
    }
}

extern "C" void kernel_launch(void* const* d_in, const int* in_sizes, int n_in,
                              void* d_out, int out_size, void* d_ws, size_t ws_size,
                              hipStream_t stream) {
    const float* targets   = (const float*)d_in[0];
    const float* neighbors = (const float*)d_in[1];
    const float* a         = (const float*)d_in[2];
    const float* kern      = (const float*)d_in[3];
    float* out = (float*)d_out;
    const int blocks = (BB * NN) / ROWS;   // 1024
    gcn_fused<<<dim3(blocks), dim3(NTHREADS), 0, stream>>>(targets, neighbors, a, kern, out);
}